// Round 1
// baseline (208.633 us; speedup 1.0000x reference)
//
#include <hip/hip_runtime.h>
#include <hip/hip_bf16.h>
#include <cstdint>

// MXFP4 fake-quant linear: out = qdq(A) @ qdq(W)^T + bias
// A: [M,K] fp32, W: [N,K] fp32, bias: [N] fp32, out: [M,N] fp32
// Design: qdq values are e2m1 * 2^e -> exactly representable in bf16.
// Pass 1: quantize A,W -> bf16 in d_ws. Pass 2: m97-style bf16 MFMA GEMM.

#define BM 128
#define BN 128
#define BK 64

typedef __bf16 bf16x8 __attribute__((ext_vector_type(8)));
typedef float floatx4 __attribute__((ext_vector_type(4)));

#define GLOBAL_AS __attribute__((address_space(1)))
#define LDS_AS __attribute__((address_space(3)))

// ---------------- quantize-dequantize (fp32 -> bf16 qdq'd) ----------------
// One thread per 1x32 block along K.

__device__ __forceinline__ float qdq1(float x, float scale, float inv) {
    float q = x * inv;                       // scale is 2^e -> exact
    q = fminf(fmaxf(q, -6.0f), 6.0f);        // clip to fp4 max
    float aq = fabsf(q);
    float ilsb = aq < 2.0f ? 2.0f : (aq < 4.0f ? 1.0f : 0.5f);
    float lsb  = aq < 2.0f ? 0.5f : (aq < 4.0f ? 1.0f : 2.0f);
    float qr = rintf(q * ilsb) * lsb;        // RNE onto e2m1 grid
    return qr * scale;                        // exact in bf16
}

__global__ void quant_mxfp4_kernel(const float* __restrict__ x,
                                   unsigned short* __restrict__ y,
                                   long nblk) {
    long t = (long)blockIdx.x * 256 + threadIdx.x;
    if (t >= nblk) return;
    const float4* xv = (const float4*)(x + t * 32);
    float4 f[8];
#pragma unroll
    for (int i = 0; i < 8; i++) f[i] = xv[i];

    float amax = 0.0f;
#pragma unroll
    for (int i = 0; i < 8; i++) {
        amax = fmaxf(amax, fmaxf(fmaxf(fabsf(f[i].x), fabsf(f[i].y)),
                                 fmaxf(fabsf(f[i].z), fabsf(f[i].w))));
    }
    // floor(log2(max(amax, tiny))) via exponent bits (exact)
    int ebits = (int)((__float_as_uint(amax) >> 23) & 0xff);
    int e = (ebits == 0 ? 1 : ebits) - 127;
    float scale, inv;
    if (amax > 0.0f) {
        scale = ldexpf(1.0f, e - 2);
        inv   = ldexpf(1.0f, 2 - e);
    } else {
        scale = 1.0f;
        inv   = 1.0f;
    }

    unsigned int pw[16];
#pragma unroll
    for (int i = 0; i < 8; i++) {
        float a0 = qdq1(f[i].x, scale, inv);
        float a1 = qdq1(f[i].y, scale, inv);
        float a2 = qdq1(f[i].z, scale, inv);
        float a3 = qdq1(f[i].w, scale, inv);
        // bf16 by truncation: values are exactly representable
        pw[2 * i]     = (__float_as_uint(a0) >> 16) | (__float_as_uint(a1) & 0xffff0000u);
        pw[2 * i + 1] = (__float_as_uint(a2) >> 16) | (__float_as_uint(a3) & 0xffff0000u);
    }
    uint4* yv = (uint4*)(y + t * 32);
#pragma unroll
    for (int i = 0; i < 4; i++)
        yv[i] = make_uint4(pw[4 * i], pw[4 * i + 1], pw[4 * i + 2], pw[4 * i + 3]);
}

// ---------------- bf16 GEMM: C[M,N] = Aq[M,K] * Wq[N,K]^T + bias ----------

__global__ void gemm_bf16_kernel(const unsigned short* __restrict__ A,
                                 const unsigned short* __restrict__ W,
                                 const float* __restrict__ bias,
                                 float* __restrict__ C,
                                 int M, int N, int K) {
    __shared__ __align__(16) unsigned short As[BM * BK];
    __shared__ __align__(16) unsigned short Ws[BN * BK];

    const int tid = threadIdx.x;
    const int lane = tid & 63;
    const int w = tid >> 6;          // wave id 0..3
    const int wr = w >> 1;           // wave row (0..1) -> 64-row half
    const int wc = w & 1;            // wave col (0..1) -> 64-col half
    const int row16 = lane & 15;
    const int quad = lane >> 4;
    const int m0 = blockIdx.y * BM;
    const int n0 = blockIdx.x * BN;

    floatx4 acc[4][4];
#pragma unroll
    for (int i = 0; i < 4; i++)
#pragma unroll
        for (int j = 0; j < 4; j++) acc[i][j] = (floatx4){0.f, 0.f, 0.f, 0.f};

    for (int k0 = 0; k0 < K; k0 += BK) {
        // Stage A tile [BM][BK] and W tile [BN][BK] (row-major, no pad) via
        // global_load_lds width 16. chunk q = it*256 + tid; row=q>>3, c8=q&7.
#pragma unroll
        for (int it = 0; it < 4; ++it) {
            int q = it * 256 + tid;
            int row = q >> 3, c8 = q & 7;
            const unsigned short* ga = A + (size_t)(m0 + row) * K + k0 + c8 * 8;
            __builtin_amdgcn_global_load_lds(
                (GLOBAL_AS void*)(ga), (LDS_AS void*)((char*)As + q * 16), 16, 0, 0);
        }
#pragma unroll
        for (int it = 0; it < 4; ++it) {
            int q = it * 256 + tid;
            int row = q >> 3, c8 = q & 7;
            const unsigned short* gw = W + (size_t)(n0 + row) * K + k0 + c8 * 8;
            __builtin_amdgcn_global_load_lds(
                (GLOBAL_AS void*)(gw), (LDS_AS void*)((char*)Ws + q * 16), 16, 0, 0);
        }
        __syncthreads();

#pragma unroll
        for (int ks = 0; ks < 2; ++ks) {
            bf16x8 af[4], wf[4];
#pragma unroll
            for (int mi = 0; mi < 4; mi++) {
                int r = wr * 64 + mi * 16 + row16;
                af[mi] = *(const bf16x8*)((const char*)As + ((size_t)r * BK + (ks * 4 + quad) * 8) * 2);
            }
#pragma unroll
            for (int ni = 0; ni < 4; ni++) {
                int r = wc * 64 + ni * 16 + row16;
                wf[ni] = *(const bf16x8*)((const char*)Ws + ((size_t)r * BK + (ks * 4 + quad) * 8) * 2);
            }
#pragma unroll
            for (int mi = 0; mi < 4; mi++)
#pragma unroll
                for (int ni = 0; ni < 4; ni++)
                    acc[mi][ni] = __builtin_amdgcn_mfma_f32_16x16x32_bf16(
                        af[mi], wf[ni], acc[mi][ni], 0, 0, 0);
        }
        __syncthreads();
    }

    // Epilogue: C/D layout col=lane&15, row=quad*4+reg
#pragma unroll
    for (int ni = 0; ni < 4; ni++) {
        int n = n0 + wc * 64 + ni * 16 + row16;
        float bv = bias[n];
#pragma unroll
        for (int mi = 0; mi < 4; mi++) {
            int mbase = m0 + wr * 64 + mi * 16 + quad * 4;
#pragma unroll
            for (int r = 0; r < 4; r++) {
                C[(size_t)(mbase + r) * N + n] = acc[mi][ni][r] + bv;
            }
        }
    }
}

// ---------------- launch ----------------

extern "C" void kernel_launch(void* const* d_in, const int* in_sizes, int n_in,
                              void* d_out, int out_size, void* d_ws, size_t ws_size,
                              hipStream_t stream) {
    const float* inp  = (const float*)d_in[0];
    const float* wgt  = (const float*)d_in[1];
    const float* bias = (const float*)d_in[2];
    float* out = (float*)d_out;

    const int N = in_sizes[2];                 // 2048
    const int K = in_sizes[1] / N;             // 2048
    const long M = (long)in_sizes[0] / K;      // 8192

    unsigned short* Aq = (unsigned short*)d_ws;
    unsigned short* Wq = Aq + (size_t)M * K;

    long ablk = (long)M * K / 32;
    long wblk = (long)N * K / 32;
    quant_mxfp4_kernel<<<dim3((ablk + 255) / 256), dim3(256), 0, stream>>>(inp, Aq, ablk);
    quant_mxfp4_kernel<<<dim3((wblk + 255) / 256), dim3(256), 0, stream>>>(wgt, Wq, wblk);

    dim3 grid(N / BN, M / BM);
    gemm_bf16_kernel<<<grid, dim3(256), 0, stream>>>(Aq, Wq, bias, out, (int)M, N, K);
}

// Round 2
// 199.408 us; speedup vs baseline: 1.0463x; 1.0463x over previous
//
#include <hip/hip_runtime.h>
#include <hip/hip_bf16.h>
#include <cstdint>

// MXFP4 fake-quant linear: out = qdq(A) @ qdq(W)^T + bias
// A: [M,K] fp32, W: [N,K] fp32, bias: [N] fp32, out: [M,N] fp32
// qdq values are e2m1 * 2^e -> exactly representable in bf16 (absmax 0.0 in R1).
// Pass 1: fused coalesced quantize A,W -> bf16 in d_ws (shuffle amax, 8 lanes/block).
// Pass 2: m97-style bf16 MFMA GEMM (128x128 tile, BK=64, global_load_lds w16).

#define BM 128
#define BN 128
#define BK 64

typedef __bf16 bf16x8 __attribute__((ext_vector_type(8)));
typedef float floatx4 __attribute__((ext_vector_type(4)));

#define GLOBAL_AS __attribute__((address_space(1)))
#define LDS_AS __attribute__((address_space(3)))

// ---------------- fused coalesced quantize-dequantize ----------------
// Lane i loads contiguous float4; 8 consecutive lanes share one 1x32 MX block.
// amax reduced with 3 shfl_xor (groups of 8 lanes stay aligned to 32-elem
// blocks because both segment sizes are multiples of 64 float4s).

__device__ __forceinline__ float qdq1(float x, float scale, float inv) {
    float q = x * inv;                       // scale is 2^e -> exact
    q = fminf(fmaxf(q, -6.0f), 6.0f);        // clip to fp4 max
    float aq = fabsf(q);
    float ilsb = aq < 2.0f ? 2.0f : (aq < 4.0f ? 1.0f : 0.5f);
    float lsb  = aq < 2.0f ? 0.5f : (aq < 4.0f ? 1.0f : 2.0f);
    float qr = rintf(q * ilsb) * lsb;        // RNE onto e2m1 grid
    return qr * scale;                        // exact in bf16
}

__global__ void quant_mxfp4_v2(const float* __restrict__ A,
                               unsigned short* __restrict__ Aq,
                               const float* __restrict__ W,
                               unsigned short* __restrict__ Wq,
                               long na4, long ntot4) {
    long t = (long)blockIdx.x * 256 + threadIdx.x;
    if (t >= ntot4) return;
    const float* src;
    unsigned short* dst;
    long idx;
    if (t < na4) { src = A; dst = Aq; idx = t; }
    else         { src = W; dst = Wq; idx = t - na4; }

    float4 f = ((const float4*)src)[idx];

    float amax = fmaxf(fmaxf(fabsf(f.x), fabsf(f.y)),
                       fmaxf(fabsf(f.z), fabsf(f.w)));
    // 8 lanes per 32-elem block: butterfly max over xor 1,2,4
    amax = fmaxf(amax, __shfl_xor(amax, 1));
    amax = fmaxf(amax, __shfl_xor(amax, 2));
    amax = fmaxf(amax, __shfl_xor(amax, 4));

    // floor(log2(amax)) via exponent bits (exact); denormals -> e = -126
    int ebits = (int)((__float_as_uint(amax) >> 23) & 0xff);
    int e = (ebits == 0 ? 1 : ebits) - 127;
    float scale, inv;
    if (amax > 0.0f) {
        scale = ldexpf(1.0f, e - 2);
        inv   = ldexpf(1.0f, 2 - e);
    } else {
        scale = 1.0f;
        inv   = 1.0f;
    }

    float a0 = qdq1(f.x, scale, inv);
    float a1 = qdq1(f.y, scale, inv);
    float a2 = qdq1(f.z, scale, inv);
    float a3 = qdq1(f.w, scale, inv);

    // bf16 by truncation: values exactly representable
    unsigned int p0 = (__float_as_uint(a0) >> 16) | (__float_as_uint(a1) & 0xffff0000u);
    unsigned int p1 = (__float_as_uint(a2) >> 16) | (__float_as_uint(a3) & 0xffff0000u);
    ((uint2*)dst)[idx] = make_uint2(p0, p1);
}

// ---------------- bf16 GEMM: C[M,N] = Aq[M,K] * Wq[N,K]^T + bias ----------

__global__ void gemm_bf16_kernel(const unsigned short* __restrict__ A,
                                 const unsigned short* __restrict__ W,
                                 const float* __restrict__ bias,
                                 float* __restrict__ C,
                                 int M, int N, int K) {
    __shared__ __align__(16) unsigned short As[BM * BK];
    __shared__ __align__(16) unsigned short Ws[BN * BK];

    const int tid = threadIdx.x;
    const int lane = tid & 63;
    const int w = tid >> 6;          // wave id 0..3
    const int wr = w >> 1;           // wave row (0..1) -> 64-row half
    const int wc = w & 1;            // wave col (0..1) -> 64-col half
    const int row16 = lane & 15;
    const int quad = lane >> 4;
    const int m0 = blockIdx.y * BM;
    const int n0 = blockIdx.x * BN;

    floatx4 acc[4][4];
#pragma unroll
    for (int i = 0; i < 4; i++)
#pragma unroll
        for (int j = 0; j < 4; j++) acc[i][j] = (floatx4){0.f, 0.f, 0.f, 0.f};

    for (int k0 = 0; k0 < K; k0 += BK) {
#pragma unroll
        for (int it = 0; it < 4; ++it) {
            int q = it * 256 + tid;
            int row = q >> 3, c8 = q & 7;
            const unsigned short* ga = A + (size_t)(m0 + row) * K + k0 + c8 * 8;
            __builtin_amdgcn_global_load_lds(
                (GLOBAL_AS void*)(ga), (LDS_AS void*)((char*)As + q * 16), 16, 0, 0);
        }
#pragma unroll
        for (int it = 0; it < 4; ++it) {
            int q = it * 256 + tid;
            int row = q >> 3, c8 = q & 7;
            const unsigned short* gw = W + (size_t)(n0 + row) * K + k0 + c8 * 8;
            __builtin_amdgcn_global_load_lds(
                (GLOBAL_AS void*)(gw), (LDS_AS void*)((char*)Ws + q * 16), 16, 0, 0);
        }
        __syncthreads();

#pragma unroll
        for (int ks = 0; ks < 2; ++ks) {
            bf16x8 af[4], wf[4];
#pragma unroll
            for (int mi = 0; mi < 4; mi++) {
                int r = wr * 64 + mi * 16 + row16;
                af[mi] = *(const bf16x8*)((const char*)As + ((size_t)r * BK + (ks * 4 + quad) * 8) * 2);
            }
#pragma unroll
            for (int ni = 0; ni < 4; ni++) {
                int r = wc * 64 + ni * 16 + row16;
                wf[ni] = *(const bf16x8*)((const char*)Ws + ((size_t)r * BK + (ks * 4 + quad) * 8) * 2);
            }
#pragma unroll
            for (int mi = 0; mi < 4; mi++)
#pragma unroll
                for (int ni = 0; ni < 4; ni++)
                    acc[mi][ni] = __builtin_amdgcn_mfma_f32_16x16x32_bf16(
                        af[mi], wf[ni], acc[mi][ni], 0, 0, 0);
        }
        __syncthreads();
    }

    // Epilogue: C/D layout col=lane&15, row=quad*4+reg
#pragma unroll
    for (int ni = 0; ni < 4; ni++) {
        int n = n0 + wc * 64 + ni * 16 + row16;
        float bv = bias[n];
#pragma unroll
        for (int mi = 0; mi < 4; mi++) {
            int mbase = m0 + wr * 64 + mi * 16 + quad * 4;
#pragma unroll
            for (int r = 0; r < 4; r++) {
                C[(size_t)(mbase + r) * N + n] = acc[mi][ni][r] + bv;
            }
        }
    }
}

// ---------------- launch ----------------

extern "C" void kernel_launch(void* const* d_in, const int* in_sizes, int n_in,
                              void* d_out, int out_size, void* d_ws, size_t ws_size,
                              hipStream_t stream) {
    const float* inp  = (const float*)d_in[0];
    const float* wgt  = (const float*)d_in[1];
    const float* bias = (const float*)d_in[2];
    float* out = (float*)d_out;

    const int N = in_sizes[2];                 // 2048
    const int K = in_sizes[1] / N;             // 2048
    const long M = (long)in_sizes[0] / K;      // 8192

    unsigned short* Aq = (unsigned short*)d_ws;
    unsigned short* Wq = Aq + (size_t)M * K;

    long na4   = (long)M * K / 4;
    long ntot4 = na4 + (long)N * K / 4;
    quant_mxfp4_v2<<<dim3((ntot4 + 255) / 256), dim3(256), 0, stream>>>(
        inp, Aq, wgt, Wq, na4, ntot4);

    dim3 grid(N / BN, M / BM);
    gemm_bf16_kernel<<<grid, dim3(256), 0, stream>>>(Aq, Wq, bias, out, (int)M, N, K);
}

// Round 3
// 158.197 us; speedup vs baseline: 1.3188x; 1.2605x over previous
//
#include <hip/hip_runtime.h>
#include <hip/hip_bf16.h>
#include <cstdint>

// MXFP4 fake-quant linear: out = qdq(A) @ qdq(W)^T + bias
// A: [M,K] fp32, W: [N,K] fp32, bias: [N] fp32, out: [M,N] fp32
// Native path: quantize to packed e2m1 (2/byte) + e8m0 scale byte per 1x32
// block, then GEMM with v_mfma_scale_f32_16x16x128_f8f6f4 (fp4 format) --
// hardware computes exactly (e2m1 * 2^(s-127)) dot products in fp32.

#define BM 128
#define BN 128
#define BKE 256   // K elements per tile iteration (2 MFMA k-steps of 128)

typedef float floatx4 __attribute__((ext_vector_type(4)));
typedef int intx8 __attribute__((ext_vector_type(8)));

#define GLOBAL_AS __attribute__((address_space(1)))
#define LDS_AS __attribute__((address_space(3)))

// ---------------- quantize fp32 -> packed fp4 + e8m0 scales ----------------
// Lane i loads contiguous float4; 8 consecutive lanes share one 1x32 block.

__device__ __forceinline__ int enc1(float x, float inv) {
    float q = x * inv;                         // inv = 2^-(e-2), exact
    q = fminf(fmaxf(q, -6.0f), 6.0f);
    int s = (int)(__float_as_uint(q) >> 31) << 3;
    float aq = fabsf(q);
    float ilsb = aq < 2.0f ? 2.0f : (aq < 4.0f ? 1.0f : 0.5f);
    float lsb  = aq < 2.0f ? 0.5f : (aq < 4.0f ? 1.0f : 2.0f);
    float ar = rintf(aq * ilsb) * lsb;         // RNE onto e2m1 grid (symmetric)
    int c;
    if (ar < 2.0f)      c = (int)(ar * 2.0f);  // 0,.5,1,1.5 -> 0..3
    else if (ar < 4.0f) c = 2 + (int)ar;       // 2,3 -> 4,5
    else                c = 4 + (int)(ar * 0.5f); // 4,6 -> 6,7
    return c | s;
}

__global__ void quant_mxfp4_v3(const float* __restrict__ A, uint8_t* __restrict__ Aq,
                               uint8_t* __restrict__ Asc,
                               const float* __restrict__ W, uint8_t* __restrict__ Wq,
                               uint8_t* __restrict__ Wsc,
                               long na4, long ntot4) {
    long t = (long)blockIdx.x * 256 + threadIdx.x;
    if (t >= ntot4) return;
    const float* src; uint8_t* dq; uint8_t* ds; long idx;
    if (t < na4) { src = A; dq = Aq; ds = Asc; idx = t; }
    else         { src = W; dq = Wq; ds = Wsc; idx = t - na4; }

    float4 f = ((const float4*)src)[idx];
    float amax = fmaxf(fmaxf(fabsf(f.x), fabsf(f.y)),
                       fmaxf(fabsf(f.z), fabsf(f.w)));
    amax = fmaxf(amax, __shfl_xor(amax, 1));
    amax = fmaxf(amax, __shfl_xor(amax, 2));
    amax = fmaxf(amax, __shfl_xor(amax, 4));

    int ebits = (int)((__float_as_uint(amax) >> 23) & 0xff);
    int sb;
    float inv;
    if (amax > 0.0f) {
        sb = ebits - 2; if (sb < 0) sb = 0;
        // inv = 2^(129 - ebits) = 2^(2 - e); exact power of two
        inv = __uint_as_float((unsigned)((256 - ebits) & 255) << 23);
    } else {
        sb = 127;              // scale 1.0, all-zero block
        inv = 0.0f;
    }

    int c0 = enc1(f.x, inv), c1 = enc1(f.y, inv);
    int c2 = enc1(f.z, inv), c3 = enc1(f.w, inv);
    // little-endian: elem 2i in low nibble of byte i
    ((unsigned short*)dq)[idx] =
        (unsigned short)(c0 | (c1 << 4) | (c2 << 8) | (c3 << 12));
    if ((idx & 7) == 0) ds[idx >> 3] = (uint8_t)sb;
}

// ---------- fp4 GEMM: C[M,N] = (Aq,As) x (Wq,Ws)^T + bias ----------
// A-frag (16x16x128): row = lane&15, k = (lane>>4)*32 + j  (16B = one 32-block)
// scale operand: e8m0 byte of that block in bits [7:0], opsel 0
// C/D: col = lane&15, row = (lane>>4)*4 + reg   (shape-determined, same as bf16)

__global__ void gemm_fp4_kernel(const uint8_t* __restrict__ Aq, const uint8_t* __restrict__ Asc,
                                const uint8_t* __restrict__ Wq, const uint8_t* __restrict__ Wsc,
                                const float* __restrict__ bias, float* __restrict__ C,
                                int M, int N, int K) {
    __shared__ __align__(16) uint8_t As4[BM * BKE / 2];  // 16 KB
    __shared__ __align__(16) uint8_t Ws4[BN * BKE / 2];  // 16 KB
    __shared__ __align__(16) uint8_t SAs[BM * 8];        // 1 KB (8 scale bytes/row)
    __shared__ __align__(16) uint8_t SWs[BN * 8];        // 1 KB

    const int tid = threadIdx.x;
    const int lane = tid & 63;
    const int w = tid >> 6;
    const int wr = w >> 1;
    const int wc = w & 1;
    const int row16 = lane & 15;
    const int quad = lane >> 4;      // k-chunk (32 elems) index
    const int sh = quad * 8;
    const int m0 = blockIdx.y * BM;
    const int n0 = blockIdx.x * BN;
    const int KB2 = K >> 1, KB32 = K >> 5;

    floatx4 acc[4][4];
#pragma unroll
    for (int i = 0; i < 4; i++)
#pragma unroll
        for (int j = 0; j < 4; j++) acc[i][j] = (floatx4){0.f, 0.f, 0.f, 0.f};

    for (int k0 = 0; k0 < K; k0 += BKE) {
        // data tiles: 16 KB each = 1024 x 16B chunks; row = 128 B = 8 chunks.
        // XOR-swizzle: LDS slot (row, c) holds global chunk (row, c ^ (row&7)).
#pragma unroll
        for (int it = 0; it < 4; ++it) {
            int q = it * 256 + tid;
            int row = q >> 3, c = q & 7;
            int cg = c ^ (row & 7);
            const uint8_t* ga = Aq + (size_t)(m0 + row) * KB2 + (k0 >> 1) + cg * 16;
            __builtin_amdgcn_global_load_lds(
                (GLOBAL_AS void*)ga, (LDS_AS void*)(As4 + q * 16), 16, 0, 0);
        }
#pragma unroll
        for (int it = 0; it < 4; ++it) {
            int q = it * 256 + tid;
            int row = q >> 3, c = q & 7;
            int cg = c ^ (row & 7);
            const uint8_t* gw = Wq + (size_t)(n0 + row) * KB2 + (k0 >> 1) + cg * 16;
            __builtin_amdgcn_global_load_lds(
                (GLOBAL_AS void*)gw, (LDS_AS void*)(Ws4 + q * 16), 16, 0, 0);
        }
        {   // scales: 8 bytes/row; thread t -> (row = t>>1, half = t&1)
            int row = tid >> 1, half = tid & 1;
            const uint8_t* gsa = Asc + (size_t)(m0 + row) * KB32 + (k0 >> 5) + half * 4;
            __builtin_amdgcn_global_load_lds(
                (GLOBAL_AS void*)gsa, (LDS_AS void*)(SAs + tid * 4), 4, 0, 0);
            const uint8_t* gsw = Wsc + (size_t)(n0 + row) * KB32 + (k0 >> 5) + half * 4;
            __builtin_amdgcn_global_load_lds(
                (GLOBAL_AS void*)gsw, (LDS_AS void*)(SWs + tid * 4), 4, 0, 0);
        }
        __syncthreads();

        uint2 sa2[4], sw2[4];
#pragma unroll
        for (int mi = 0; mi < 4; mi++)
            sa2[mi] = *(const uint2*)(SAs + (wr * 64 + mi * 16 + row16) * 8);
#pragma unroll
        for (int ni = 0; ni < 4; ni++)
            sw2[ni] = *(const uint2*)(SWs + (wc * 64 + ni * 16 + row16) * 8);

#pragma unroll
        for (int ks = 0; ks < 2; ++ks) {
            int4 af[4], wf[4];
#pragma unroll
            for (int mi = 0; mi < 4; mi++) {
                int r = wr * 64 + mi * 16 + row16;
                int c = ((ks * 4 + quad) ^ (r & 7)) * 16;
                af[mi] = *(const int4*)(As4 + r * 128 + c);
            }
#pragma unroll
            for (int ni = 0; ni < 4; ni++) {
                int r = wc * 64 + ni * 16 + row16;
                int c = ((ks * 4 + quad) ^ (r & 7)) * 16;
                wf[ni] = *(const int4*)(Ws4 + r * 128 + c);
            }
            int sas[4], sws[4];
#pragma unroll
            for (int mi = 0; mi < 4; mi++)
                sas[mi] = (int)(((ks ? sa2[mi].y : sa2[mi].x) >> sh) & 0xff);
#pragma unroll
            for (int ni = 0; ni < 4; ni++)
                sws[ni] = (int)(((ks ? sw2[ni].y : sw2[ni].x) >> sh) & 0xff);

#pragma unroll
            for (int mi = 0; mi < 4; mi++) {
                intx8 a8 = {af[mi].x, af[mi].y, af[mi].z, af[mi].w, 0, 0, 0, 0};
#pragma unroll
                for (int ni = 0; ni < 4; ni++) {
                    intx8 b8 = {wf[ni].x, wf[ni].y, wf[ni].z, wf[ni].w, 0, 0, 0, 0};
                    acc[mi][ni] = __builtin_amdgcn_mfma_scale_f32_16x16x128_f8f6f4(
                        a8, b8, acc[mi][ni], 4, 4, 0, sas[mi], 0, sws[ni]);
                }
            }
        }
        __syncthreads();
    }

    // Epilogue: C/D layout col=lane&15, row=quad*4+reg
#pragma unroll
    for (int ni = 0; ni < 4; ni++) {
        int n = n0 + wc * 64 + ni * 16 + row16;
        float bv = bias[n];
#pragma unroll
        for (int mi = 0; mi < 4; mi++) {
            int mbase = m0 + wr * 64 + mi * 16 + quad * 4;
#pragma unroll
            for (int r = 0; r < 4; r++) {
                C[(size_t)(mbase + r) * N + n] = acc[mi][ni][r] + bv;
            }
        }
    }
}

// ---------------- launch ----------------

extern "C" void kernel_launch(void* const* d_in, const int* in_sizes, int n_in,
                              void* d_out, int out_size, void* d_ws, size_t ws_size,
                              hipStream_t stream) {
    const float* inp  = (const float*)d_in[0];
    const float* wgt  = (const float*)d_in[1];
    const float* bias = (const float*)d_in[2];
    float* out = (float*)d_out;

    const int N = in_sizes[2];                 // 2048
    const int K = in_sizes[1] / N;             // 2048
    const long M = (long)in_sizes[0] / K;      // 8192

    uint8_t* Aq4 = (uint8_t*)d_ws;             // M*K/2
    uint8_t* Wq4 = Aq4 + (size_t)M * K / 2;    // N*K/2
    uint8_t* Asc = Wq4 + (size_t)N * K / 2;    // M*K/32
    uint8_t* Wsc = Asc + (size_t)M * K / 32;   // N*K/32

    long na4   = (long)M * K / 4;
    long ntot4 = na4 + (long)N * K / 4;
    quant_mxfp4_v3<<<dim3((ntot4 + 255) / 256), dim3(256), 0, stream>>>(
        inp, Aq4, Asc, wgt, Wq4, Wsc, na4, ntot4);

    dim3 grid(N / BN, M / BM);
    gemm_fp4_kernel<<<grid, dim3(256), 0, stream>>>(
        Aq4, Asc, Wq4, Wsc, bias, out, (int)M, N, K);
}